// Round 14
// baseline (761.649 us; speedup 1.0000x reference)
//
#include <hip/hip_runtime.h>
#include <hip/hip_bf16.h>

#define NN   30000
#define EE   960000
#define IND  2048
#define NEMB 64
#define NH1  32
#define NH2  16
#define NET  64
#define NB   16
#define NBLK 1024

typedef __bf16 bf8 __attribute__((ext_vector_type(8)));
typedef __bf16 bf4 __attribute__((ext_vector_type(4)));
typedef __bf16 bf2 __attribute__((ext_vector_type(2)));
typedef float  f4  __attribute__((ext_vector_type(4)));

#define AS3 __attribute__((address_space(3)))
#define AS1 __attribute__((address_space(1)))

__device__ __forceinline__ void gll16(const void* g, void* l) {
    __builtin_amdgcn_global_load_lds((const AS1 unsigned int*)g,
                                     (AS3 unsigned int*)l, 16, 0, 0);
}

__device__ __forceinline__ bf8 bf8_zero() {
    bf8 z;
#pragma unroll
    for (int i = 0; i < 8; i++) z[i] = (__bf16)0.0f;
    return z;
}

// grid barrier: bar[0]=arrive count, bar[1]=generation (both zeroed per call)
__device__ __forceinline__ void gridbar(int* bar, int target) {
    __syncthreads();
    if (threadIdx.x == 0) {
        __threadfence();                                   // release
        if (atomicAdd(&bar[0], 1) == NBLK - 1) {
            bar[0] = 0;                                    // nobody reads cnt while spinning
            __threadfence();
            atomicAdd(&bar[1], 1);                         // gen -> target
        }
        while (atomicAdd(&bar[1], 0) < target) __builtin_amdgcn_s_sleep(8);
        __threadfence();                                   // acquire (L1 inv)
    }
    __syncthreads();
}

__global__ __launch_bounds__(256, 4) void k_mega(
        const float* __restrict__ x, const int* __restrict__ ei, const int* __restrict__ et,
        const float* __restrict__ xnorm, const float* __restrict__ embed,
        const float* __restrict__ basis1, const float* __restrict__ att1,
        const float* __restrict__ root1, const float* __restrict__ bias1,
        const float* __restrict__ basis2, const float* __restrict__ att2,
        const float* __restrict__ root2, const float* __restrict__ bias2,
        __bf16* __restrict__ embT, __bf16* __restrict__ W1T, __bf16* __restrict__ W2T,
        __bf16* __restrict__ h0b, float* __restrict__ out1, __bf16* __restrict__ h1b,
        float* __restrict__ out, int* __restrict__ bar) {
    __shared__ __align__(16) char smem[32768];
    int b = blockIdx.x, t = threadIdx.x;
    int wv = t >> 6, lane = t & 63;
    int l15 = lane & 15, kg = lane >> 4;

    // ================= P1: prep (embT + W1T + W2T) =================
    if (b < 512) {
        int idx = b * 256 + t;                  // embT[n][k] = embed[k][n]
        int n = idx >> 11, k = idx & 2047;
        embT[idx] = (__bf16)embed[k * NEMB + n];
    } else if (b < 576) {
        int r = b - 512;
        float* a = (float*)smem;
        if (t < NB) a[t] = att1[r * NB + t];
        __syncthreads();
        for (int idx = t; idx < NH1 * NEMB; idx += 256) {
            int o = idx >> 6, i = idx & 63;
            float acc = 0.f;
#pragma unroll
            for (int bb = 0; bb < NB; bb++) acc += a[bb] * basis1[(bb * NEMB + i) * NH1 + o];
            W1T[r * (NH1 * NEMB) + idx] = (__bf16)acc;
        }
    } else if (b < 640) {
        int r = b - 576;
        float* a = (float*)smem;
        if (t < NB) a[t] = att2[r * NB + t];
        __syncthreads();
        for (int idx = t; idx < NH2 * NH1; idx += 256) {
            int o = idx >> 5, i = idx & 31;
            float acc = 0.f;
#pragma unroll
            for (int bb = 0; bb < NB; bb++) acc += a[bb] * basis2[(bb * NH1 + i) * NH2 + o];
            W2T[r * (NH2 * NH1) + idx] = (__bf16)acc;
        }
    }
    gridbar(bar, 1);

    // ================= P2: embed GEMM (BK=64 dbuf) + fused init1 =================
    if (b < 938) {
        int rowbase = b * 32;
        int q16 = lane >> 4, slot16 = lane & 15;    // A: 4 rows/KB
        int r8i = lane >> 3, slot8 = lane & 7;      // B: 8 rows/KB
        int n = wv * 16 + l15;
        int bswz = (n & 7) << 4;
        int aswz = (l15 & 7) << 4;
        f4 acc0 = (f4)0.0f, acc1 = (f4)0.0f;

        auto STAGE = [&](int c, int buf) {
#pragma unroll
            for (int i = 0; i < 2; i++) {           // A: 2 gll/wave (4 rows x 256B each)
                int rp = wv * 2 + i;
                int row = rp * 4 + q16;
                int grow = rowbase + row;
                if (grow >= NN) grow = NN - 1;
                const char* g = (const char*)x + (size_t)grow * (IND * 4) + c * 256
                              + ((slot16 * 16) ^ ((row & 7) << 4));
                gll16(g, smem + buf * 8192 + rp * 1024);
            }
#pragma unroll
            for (int i = 0; i < 2; i++) {           // B: 2 gll/wave (8 rows x 128B each)
                int rp = wv * 2 + i;
                int row = rp * 8 + r8i;
                const char* g = (const char*)embT + (size_t)row * (IND * 2) + c * 128
                              + ((slot8 * 16) ^ ((row & 7) << 4));
                gll16(g, smem + 16384 + buf * 8192 + rp * 1024);
            }
        };

        STAGE(0, 0);
        for (int c = 0; c < 32; c++) {
            int buf = c & 1;
            if (c < 31) {
                STAGE(c + 1, buf ^ 1);
                asm volatile("s_waitcnt vmcnt(4)" ::: "memory");
            } else {
                asm volatile("s_waitcnt vmcnt(0)" ::: "memory");
            }
            __builtin_amdgcn_s_barrier();
            __builtin_amdgcn_sched_barrier(0);
            const char* bufA = smem + buf * 8192;
            const char* bufB = smem + 16384 + buf * 8192;
            const char* bsrow = bufB + n * 128;
            const char* ar0 = bufA + l15 * 256;
            const char* ar1 = bufA + (l15 + 16) * 256;
#pragma unroll
            for (int kk = 0; kk < 2; kk++) {
                int aoff = (kg * 32 + kk * 128) ^ aswz;
                float4 lo0 = *(const float4*)(ar0 + aoff);
                float4 hi0 = *(const float4*)(ar0 + (aoff ^ 16));
                float4 lo1 = *(const float4*)(ar1 + aoff);
                float4 hi1 = *(const float4*)(ar1 + (aoff ^ 16));
                bf8 bb = *(const bf8*)(bsrow + ((kg * 16 + kk * 64) ^ bswz));
                bf8 a0, a1;
                a0[0]=(__bf16)lo0.x; a0[1]=(__bf16)lo0.y; a0[2]=(__bf16)lo0.z; a0[3]=(__bf16)lo0.w;
                a0[4]=(__bf16)hi0.x; a0[5]=(__bf16)hi0.y; a0[6]=(__bf16)hi0.z; a0[7]=(__bf16)hi0.w;
                a1[0]=(__bf16)lo1.x; a1[1]=(__bf16)lo1.y; a1[2]=(__bf16)lo1.z; a1[3]=(__bf16)lo1.w;
                a1[4]=(__bf16)hi1.x; a1[5]=(__bf16)hi1.y; a1[6]=(__bf16)hi1.z; a1[7]=(__bf16)hi1.w;
                acc0 = __builtin_amdgcn_mfma_f32_16x16x32_bf16(a0, bb, acc0, 0, 0, 0);
                acc1 = __builtin_amdgcn_mfma_f32_16x16x32_bf16(a1, bb, acc1, 0, 0, 0);
            }
            __builtin_amdgcn_sched_barrier(0);
            __builtin_amdgcn_s_barrier();
        }
        // epilogue: h0 -> global + LDS, then fused init1
        __bf16* h0s = (__bf16*)smem;            // 32 x 64 bf16 = 4 KB
#pragma unroll
        for (int j = 0; j < 4; j++) {
            int lr0 = kg * 4 + j, lr1 = lr0 + 16;
            int r0 = rowbase + lr0, r1 = rowbase + lr1;
            float v0 = 0.f, v1 = 0.f;
            if (r0 < NN) v0 = acc0[j] / xnorm[r0];
            if (r1 < NN) v1 = acc1[j] / xnorm[r1];
            __bf16 b0 = (__bf16)v0, b1 = (__bf16)v1;
            if (r0 < NN) h0b[(size_t)r0 * NEMB + n] = b0;
            if (r1 < NN) h0b[(size_t)r1 * NEMB + n] = b1;
            h0s[lr0 * NEMB + n] = b0;
            h0s[lr1 * NEMB + n] = b1;
        }
        __syncthreads();
        {
            int row = t >> 3, c0 = (t & 7) * 4;
            int grow = rowbase + row;
            if (grow < NN) {
                const __bf16* hr = h0s + row * NEMB;
                float4 acc = *(const float4*)(bias1 + c0);
#pragma unroll
                for (int k = 0; k < NEMB; k++) {
                    float a = (float)hr[k];
                    float4 w = *(const float4*)(root1 + k * NH1 + c0);
                    acc.x += a * w.x; acc.y += a * w.y;
                    acc.z += a * w.z; acc.w += a * w.w;
                }
                *(float4*)(out1 + (size_t)grow * NH1 + c0) = acc;
            }
        }
    }
    gridbar(bar, 2);

    // ================= P3: edge layer 1 (atomic scatter) =================
    {
        bf8 zero = bf8_zero();
        for (int wid = b * 4 + wv; wid < NN; wid += NBLK * 4) {
            int er0 = wid * 32 + l15, er1 = er0 + 16;
            int et0v = et[er0],  et1v = et[er1];
            int src0 = ei[er0],  src1 = ei[er1];
            int dst0 = ei[EE + er0], dst1 = ei[EE + er1];
            const __bf16* hp0 = h0b + (size_t)src0 * NEMB + kg * 8;
            const __bf16* hp1 = h0b + (size_t)src1 * NEMB + kg * 8;
            bf8 a00 = *(const bf8*)hp0;
            bf8 a01 = *(const bf8*)(hp0 + 32);
            bf8 a10 = *(const bf8*)hp1;
            bf8 a11 = *(const bf8*)(hp1 + 32);
#pragma unroll
            for (int s = 0; s < 2; s++) {
                int my_et = s ? et1v : et0v;
                int my_dst = s ? dst1 : dst0;
                bf8 a0 = s ? a10 : a00;
                bf8 a1 = s ? a11 : a01;
                f4 c0 = (f4)0.0f, c1 = (f4)0.0f;
                int pos = 0;
                while (pos < 16) {
                    int r = __shfl(my_et, pos);
                    unsigned long long bl = __ballot(my_et == r);
                    unsigned m16 = (unsigned)(bl & 0xFFFFull);
                    int run = __builtin_ctz(~(m16 >> pos));
                    int end = pos + run;
                    const __bf16* wb = W1T + (size_t)r * (NH1 * NEMB) + (size_t)l15 * NEMB + kg * 8;
                    bf8 b00 = *(const bf8*)(wb);
                    bf8 b01 = *(const bf8*)(wb + 32);
                    bf8 b10 = *(const bf8*)(wb + 16 * NEMB);
                    bf8 b11 = *(const bf8*)(wb + 16 * NEMB + 32);
                    bool use = (l15 >= pos) && (l15 < end);
                    bf8 ua0 = use ? a0 : zero;
                    bf8 ua1 = use ? a1 : zero;
                    c0 = __builtin_amdgcn_mfma_f32_16x16x32_bf16(ua0, b00, c0, 0, 0, 0);
                    c0 = __builtin_amdgcn_mfma_f32_16x16x32_bf16(ua1, b01, c0, 0, 0, 0);
                    c1 = __builtin_amdgcn_mfma_f32_16x16x32_bf16(ua0, b10, c1, 0, 0, 0);
                    c1 = __builtin_amdgcn_mfma_f32_16x16x32_bf16(ua1, b11, c1, 0, 0, 0);
                    pos = end;
                }
#pragma unroll
                for (int j = 0; j < 4; j++) {
                    int eidx = kg * 4 + j;
                    int dst = __shfl(my_dst, eidx);
                    atomicAdd(out1 + (size_t)dst * NH1 + l15,      c0[j]);
                    atomicAdd(out1 + (size_t)dst * NH1 + 16 + l15, c1[j]);
                }
            }
        }
    }
    gridbar(bar, 3);

    // ================= P4: mid (relu -> h1b, init2 -> out) =================
    for (int rb = b; rb < 1875; rb += NBLK) {
        int row = rb * 16 + (t >> 4);
        int col = t & 15;
        const float* orow = out1 + (size_t)row * NH1;
        float h[NH1];
#pragma unroll
        for (int k = 0; k < NH1; k++) h[k] = fmaxf(orow[k], 0.f);
        bf2 hb;
        hb[0] = (__bf16)h[2 * col];
        hb[1] = (__bf16)h[2 * col + 1];
        *(bf2*)(h1b + (size_t)row * NH1 + 2 * col) = hb;
        float acc = bias2[col];
#pragma unroll
        for (int k = 0; k < NH1; k++) acc += h[k] * root2[k * NH2 + col];
        out[(size_t)row * NH2 + col] = acc;
    }
    gridbar(bar, 4);

    // ================= P5: edge layer 2 (atomic scatter) =================
    {
        bf8 zero = bf8_zero();
        for (int wid = b * 4 + wv; wid < NN; wid += NBLK * 4) {
            int er0 = wid * 32 + l15, er1 = er0 + 16;
            int et0v = et[er0],  et1v = et[er1];
            int src0 = ei[er0],  src1 = ei[er1];
            int dst0 = ei[EE + er0], dst1 = ei[EE + er1];
            bf8 ab0 = *(const bf8*)(h1b + (size_t)src0 * NH1 + kg * 8);
            bf8 ab1 = *(const bf8*)(h1b + (size_t)src1 * NH1 + kg * 8);
#pragma unroll
            for (int s = 0; s < 2; s++) {
                int my_et = s ? et1v : et0v;
                int my_dst = s ? dst1 : dst0;
                bf8 a = s ? ab1 : ab0;
                f4 c = (f4)0.0f;
                int pos = 0;
                while (pos < 16) {
                    int r = __shfl(my_et, pos);
                    unsigned long long bl = __ballot(my_et == r);
                    unsigned m16 = (unsigned)(bl & 0xFFFFull);
                    int run = __builtin_ctz(~(m16 >> pos));
                    int end = pos + run;
                    bf8 bb = *(const bf8*)(W2T + (size_t)r * (NH2 * NH1) + (size_t)l15 * NH1 + kg * 8);
                    bool use = (l15 >= pos) && (l15 < end);
                    c = __builtin_amdgcn_mfma_f32_16x16x32_bf16(use ? a : zero, bb, c, 0, 0, 0);
                    pos = end;
                }
#pragma unroll
                for (int j = 0; j < 4; j++) {
                    int eidx = kg * 4 + j;
                    int dst = __shfl(my_dst, eidx);
                    atomicAdd(out + (size_t)dst * NH2 + l15, c[j]);
                }
            }
        }
    }
    gridbar(bar, 5);

    // ================= P6: relu2 in place on out =================
    for (int i = b * 256 + t; i < NN * NH2 / 4; i += NBLK * 256) {
        float4 v = ((float4*)out)[i];
        v.x = fmaxf(v.x, 0.f); v.y = fmaxf(v.y, 0.f);
        v.z = fmaxf(v.z, 0.f); v.w = fmaxf(v.w, 0.f);
        ((float4*)out)[i] = v;
    }
}

// ---------------- launch ----------------
extern "C" void kernel_launch(void* const* d_in, const int* in_sizes, int n_in,
                              void* d_out, int out_size, void* d_ws, size_t ws_size,
                              hipStream_t stream) {
    const float* x      = (const float*)d_in[0];
    const int*   ei     = (const int*)d_in[1];
    const int*   et     = (const int*)d_in[2];
    const float* xnorm  = (const float*)d_in[4];
    const float* embed  = (const float*)d_in[5];
    const float* basis1 = (const float*)d_in[6];
    const float* att1   = (const float*)d_in[7];
    const float* root1  = (const float*)d_in[8];
    const float* bias1  = (const float*)d_in[9];
    const float* basis2 = (const float*)d_in[10];
    const float* att2   = (const float*)d_in[11];
    const float* root2  = (const float*)d_in[12];
    const float* bias2  = (const float*)d_in[13];
    float* out = (float*)d_out;

    char* ws = (char*)d_ws;
    __bf16* embT = (__bf16*)(ws + 0);              //   262,144
    __bf16* W1T  = (__bf16*)(ws + 262144);         //   262,144
    __bf16* W2T  = (__bf16*)(ws + 524288);         //    65,536
    __bf16* h0b  = (__bf16*)(ws + 589824);         // 3,840,000
    float*  out1 = (float*) (ws + 4429824);        // 3,840,000
    __bf16* h1b  = (__bf16*)(ws + 8269824);        // 1,920,000
    int*    bar  = (int*)   (ws + 10189824);       //        64  (end ~10.2 MB)

    hipMemsetAsync(bar, 0, 64, stream);
    k_mega<<<NBLK, 256, 0, stream>>>(x, ei, et, xnorm, embed, basis1, att1, root1, bias1,
                                     basis2, att2, root2, bias2,
                                     embT, W1T, W2T, h0b, out1, h1b, out, bar);
}

// Round 15
// 473.493 us; speedup vs baseline: 1.6086x; 1.6086x over previous
//
#include <hip/hip_runtime.h>
#include <hip/hip_bf16.h>

#define NN   30000
#define EE   960000
#define IND  2048
#define NEMB 64
#define NH1  32
#define NH2  16
#define NET  64
#define NB   16
#define NBLK 256
#define THR  1024

typedef __bf16 bf8 __attribute__((ext_vector_type(8)));
typedef __bf16 bf4 __attribute__((ext_vector_type(4)));
typedef __bf16 bf2 __attribute__((ext_vector_type(2)));
typedef float  f4  __attribute__((ext_vector_type(4)));

#define AS3 __attribute__((address_space(3)))
#define AS1 __attribute__((address_space(1)))

__device__ __forceinline__ void gll16(const void* g, void* l) {
    __builtin_amdgcn_global_load_lds((const AS1 unsigned int*)g,
                                     (AS3 unsigned int*)l, 16, 0, 0);
}

__device__ __forceinline__ bf8 bf8_zero() {
    bf8 z;
#pragma unroll
    for (int i = 0; i < 8; i++) z[i] = (__bf16)0.0f;
    return z;
}

// grid barrier: bar[0]=arrive count, bar[1]=generation (zeroed per call by memset).
// Arrive = one RMW per block; wait = LOAD-only polling with s_sleep backoff
// (r14's RMW-spin was the disaster: 1024 cross-XCD RMWs on one line).
__device__ __forceinline__ void gridbar(int* bar, int target) {
    __syncthreads();
    if (threadIdx.x == 0) {
        __threadfence();                               // release prior writes
        if (atomicAdd(&bar[0], 1) == NBLK - 1) {
            bar[0] = 0;
            __threadfence();
            atomicAdd(&bar[1], 1);                     // gen -> target
        }
        while (__hip_atomic_load(&bar[1], __ATOMIC_ACQUIRE,
                                 __HIP_MEMORY_SCOPE_AGENT) < target)
            __builtin_amdgcn_s_sleep(32);
        __threadfence();                               // acquire
    }
    __syncthreads();
}

__global__ __launch_bounds__(THR, 1) void k_mega(
        const float* __restrict__ x, const int* __restrict__ ei, const int* __restrict__ et,
        const float* __restrict__ xnorm, const float* __restrict__ embed,
        const float* __restrict__ basis1, const float* __restrict__ att1,
        const float* __restrict__ root1, const float* __restrict__ bias1,
        const float* __restrict__ basis2, const float* __restrict__ att2,
        const float* __restrict__ root2, const float* __restrict__ bias2,
        __bf16* __restrict__ embT, __bf16* __restrict__ W1T, __bf16* __restrict__ W2T,
        __bf16* __restrict__ h0b, float* __restrict__ out1, __bf16* __restrict__ h1b,
        float* __restrict__ out, int* __restrict__ bar) {
    __shared__ __align__(16) char smem[131072];        // 128 KB: 4 engines x 32 KB
    int b = blockIdx.x, t = threadIdx.x;
    int wv = t >> 6, lane = t & 63;
    int l15 = lane & 15, kg = lane >> 4;

    // ================= P1: prep (W1T | W2T | embT by block range) =================
    if (b < 64) {
        int r = b;
        float* a = (float*)smem;
        if (t < NB) a[t] = att1[r * NB + t];
        __syncthreads();
        for (int idx = t; idx < NH1 * NEMB; idx += THR) {
            int o = idx >> 6, i = idx & 63;
            float acc = 0.f;
#pragma unroll
            for (int bb = 0; bb < NB; bb++) acc += a[bb] * basis1[(bb * NEMB + i) * NH1 + o];
            W1T[r * (NH1 * NEMB) + idx] = (__bf16)acc;
        }
    } else if (b < 128) {
        int r = b - 64;
        float* a = (float*)smem;
        if (t < NB) a[t] = att2[r * NB + t];
        __syncthreads();
        if (t < NH2 * NH1) {
            int o = t >> 5, i = t & 31;
            float acc = 0.f;
#pragma unroll
            for (int bb = 0; bb < NB; bb++) acc += a[bb] * basis2[(bb * NH1 + i) * NH2 + o];
            W2T[r * (NH2 * NH1) + t] = (__bf16)acc;
        }
    } else {
        int idx = (b - 128) * THR + t;                 // 128 blocks x 1024 = 131072 exact
        int n = idx >> 11, k = idx & 2047;
        embT[idx] = (__bf16)embed[k * NEMB + n];
    }
    gridbar(bar, 1);

    // ================= P2: embed GEMM, 1024 engines x (32 rows, BK=64 dbuf) ========
    {
        int eng = b * 4 + (wv >> 2);                   // [0,1024)
        int wsub = wv & 3;
        int tile = eng < 938 ? eng : 937;              // tail engines duplicate (idempotent)
        int rowbase = tile * 32;
        char* base = smem + (wv >> 2) * 32768;         // A:0..16K (dbuf 8K), B:16K..32K
        int q16 = lane >> 4, slot16 = lane & 15;       // A: 4 rows/KB
        int r8i = lane >> 3, slot8 = lane & 7;         // B: 8 rows/KB
        int n = wsub * 16 + l15;
        int bswz = (n & 7) << 4;
        int aswz = (l15 & 7) << 4;
        f4 acc0 = (f4)0.0f, acc1 = (f4)0.0f;

        auto STAGE = [&](int c, int buf) {
#pragma unroll
            for (int i = 0; i < 2; i++) {              // A: 2 gll/wave (4 rows x 256B)
                int rp = wsub * 2 + i;
                int row = rp * 4 + q16;
                int grow = rowbase + row;
                if (grow >= NN) grow = NN - 1;
                const char* g = (const char*)x + (size_t)grow * (IND * 4) + c * 256
                              + ((slot16 * 16) ^ ((row & 7) << 4));
                gll16(g, base + buf * 8192 + rp * 1024);
            }
#pragma unroll
            for (int i = 0; i < 2; i++) {              // B: 2 gll/wave (8 rows x 128B)
                int rp = wsub * 2 + i;
                int row = rp * 8 + r8i;
                const char* g = (const char*)embT + (size_t)row * (IND * 2) + c * 128
                              + ((slot8 * 16) ^ ((row & 7) << 4));
                gll16(g, base + 16384 + buf * 8192 + rp * 1024);
            }
        };

        STAGE(0, 0);
        for (int c = 0; c < 32; c++) {
            int buf = c & 1;
            if (c < 31) {
                STAGE(c + 1, buf ^ 1);
                asm volatile("s_waitcnt vmcnt(4)" ::: "memory");
            } else {
                asm volatile("s_waitcnt vmcnt(0)" ::: "memory");
            }
            __builtin_amdgcn_s_barrier();
            __builtin_amdgcn_sched_barrier(0);
            const char* bufA = base + buf * 8192;
            const char* bufB = base + 16384 + buf * 8192;
            const char* bsrow = bufB + n * 128;
            const char* ar0 = bufA + l15 * 256;
            const char* ar1 = bufA + (l15 + 16) * 256;
#pragma unroll
            for (int kk = 0; kk < 2; kk++) {
                int aoff = (kg * 32 + kk * 128) ^ aswz;
                float4 lo0 = *(const float4*)(ar0 + aoff);
                float4 hi0 = *(const float4*)(ar0 + (aoff ^ 16));
                float4 lo1 = *(const float4*)(ar1 + aoff);
                float4 hi1 = *(const float4*)(ar1 + (aoff ^ 16));
                bf8 bb = *(const bf8*)(bsrow + ((kg * 16 + kk * 64) ^ bswz));
                bf8 a0, a1;
                a0[0]=(__bf16)lo0.x; a0[1]=(__bf16)lo0.y; a0[2]=(__bf16)lo0.z; a0[3]=(__bf16)lo0.w;
                a0[4]=(__bf16)hi0.x; a0[5]=(__bf16)hi0.y; a0[6]=(__bf16)hi0.z; a0[7]=(__bf16)hi0.w;
                a1[0]=(__bf16)lo1.x; a1[1]=(__bf16)lo1.y; a1[2]=(__bf16)lo1.z; a1[3]=(__bf16)lo1.w;
                a1[4]=(__bf16)hi1.x; a1[5]=(__bf16)hi1.y; a1[6]=(__bf16)hi1.z; a1[7]=(__bf16)hi1.w;
                acc0 = __builtin_amdgcn_mfma_f32_16x16x32_bf16(a0, bb, acc0, 0, 0, 0);
                acc1 = __builtin_amdgcn_mfma_f32_16x16x32_bf16(a1, bb, acc1, 0, 0, 0);
            }
            __builtin_amdgcn_sched_barrier(0);
            __builtin_amdgcn_s_barrier();
        }
        // epilogue: h0 -> global + engine LDS, then fused init1 (engine-local)
        __bf16* h0s = (__bf16*)base;                   // 32 x 64 bf16 = 4 KB
#pragma unroll
        for (int j = 0; j < 4; j++) {
            int lr0 = kg * 4 + j, lr1 = lr0 + 16;
            int r0 = rowbase + lr0, r1 = rowbase + lr1;
            float v0 = 0.f, v1 = 0.f;
            if (r0 < NN) v0 = acc0[j] / xnorm[r0];
            if (r1 < NN) v1 = acc1[j] / xnorm[r1];
            __bf16 b0 = (__bf16)v0, b1 = (__bf16)v1;
            if (r0 < NN) h0b[(size_t)r0 * NEMB + n] = b0;
            if (r1 < NN) h0b[(size_t)r1 * NEMB + n] = b1;
            h0s[lr0 * NEMB + n] = b0;
            h0s[lr1 * NEMB + n] = b1;
        }
        __syncthreads();
        {
            int te = wsub * 64 + lane;                 // engine-local thread id [0,256)
            int row = te >> 3, c0 = (te & 7) * 4;
            int grow = rowbase + row;
            if (grow < NN) {
                const __bf16* hr = h0s + row * NEMB;
                float4 acc = *(const float4*)(bias1 + c0);
#pragma unroll
                for (int k = 0; k < NEMB; k++) {
                    float a = (float)hr[k];
                    float4 w = *(const float4*)(root1 + k * NH1 + c0);
                    acc.x += a * w.x; acc.y += a * w.y;
                    acc.z += a * w.z; acc.w += a * w.w;
                }
                *(float4*)(out1 + (size_t)grow * NH1 + c0) = acc;
            }
        }
    }
    gridbar(bar, 2);

    // ================= P3: edge layer 1 (atomic scatter) =================
    {
        bf8 zero = bf8_zero();
        for (int wid = b * 16 + wv; wid < NN; wid += NBLK * 16) {
            int er0 = wid * 32 + l15, er1 = er0 + 16;
            int et0v = et[er0],  et1v = et[er1];
            int src0 = ei[er0],  src1 = ei[er1];
            int dst0 = ei[EE + er0], dst1 = ei[EE + er1];
            const __bf16* hp0 = h0b + (size_t)src0 * NEMB + kg * 8;
            const __bf16* hp1 = h0b + (size_t)src1 * NEMB + kg * 8;
            bf8 a00 = *(const bf8*)hp0;
            bf8 a01 = *(const bf8*)(hp0 + 32);
            bf8 a10 = *(const bf8*)hp1;
            bf8 a11 = *(const bf8*)(hp1 + 32);
#pragma unroll
            for (int s = 0; s < 2; s++) {
                int my_et = s ? et1v : et0v;
                int my_dst = s ? dst1 : dst0;
                bf8 a0 = s ? a10 : a00;
                bf8 a1 = s ? a11 : a01;
                f4 c0 = (f4)0.0f, c1 = (f4)0.0f;
                int pos = 0;
                while (pos < 16) {
                    int r = __shfl(my_et, pos);
                    unsigned long long bl = __ballot(my_et == r);
                    unsigned m16 = (unsigned)(bl & 0xFFFFull);
                    int run = __builtin_ctz(~(m16 >> pos));
                    int end = pos + run;
                    const __bf16* wb = W1T + (size_t)r * (NH1 * NEMB) + (size_t)l15 * NEMB + kg * 8;
                    bf8 b00 = *(const bf8*)(wb);
                    bf8 b01 = *(const bf8*)(wb + 32);
                    bf8 b10 = *(const bf8*)(wb + 16 * NEMB);
                    bf8 b11 = *(const bf8*)(wb + 16 * NEMB + 32);
                    bool use = (l15 >= pos) && (l15 < end);
                    bf8 ua0 = use ? a0 : zero;
                    bf8 ua1 = use ? a1 : zero;
                    c0 = __builtin_amdgcn_mfma_f32_16x16x32_bf16(ua0, b00, c0, 0, 0, 0);
                    c0 = __builtin_amdgcn_mfma_f32_16x16x32_bf16(ua1, b01, c0, 0, 0, 0);
                    c1 = __builtin_amdgcn_mfma_f32_16x16x32_bf16(ua0, b10, c1, 0, 0, 0);
                    c1 = __builtin_amdgcn_mfma_f32_16x16x32_bf16(ua1, b11, c1, 0, 0, 0);
                    pos = end;
                }
#pragma unroll
                for (int j = 0; j < 4; j++) {
                    int eidx = kg * 4 + j;
                    int dst = __shfl(my_dst, eidx);
                    atomicAdd(out1 + (size_t)dst * NH1 + l15,      c0[j]);
                    atomicAdd(out1 + (size_t)dst * NH1 + 16 + l15, c1[j]);
                }
            }
        }
    }
    gridbar(bar, 3);

    // ================= P4: mid (relu -> h1b, init2 -> out) =================
    for (int rb = b; rb < 469; rb += NBLK) {
        int row = rb * 64 + (t >> 4);
        int col = t & 15;
        if (row < NN) {
            const float* orow = out1 + (size_t)row * NH1;
            float h[NH1];
#pragma unroll
            for (int k = 0; k < NH1; k++) h[k] = fmaxf(orow[k], 0.f);
            bf2 hb;
            hb[0] = (__bf16)h[2 * col];
            hb[1] = (__bf16)h[2 * col + 1];
            *(bf2*)(h1b + (size_t)row * NH1 + 2 * col) = hb;
            float acc = bias2[col];
#pragma unroll
            for (int k = 0; k < NH1; k++) acc += h[k] * root2[k * NH2 + col];
            out[(size_t)row * NH2 + col] = acc;
        }
    }
    gridbar(bar, 4);

    // ================= P5: edge layer 2 (atomic scatter) =================
    {
        bf8 zero = bf8_zero();
        for (int wid = b * 16 + wv; wid < NN; wid += NBLK * 16) {
            int er0 = wid * 32 + l15, er1 = er0 + 16;
            int et0v = et[er0],  et1v = et[er1];
            int src0 = ei[er0],  src1 = ei[er1];
            int dst0 = ei[EE + er0], dst1 = ei[EE + er1];
            bf8 ab0 = *(const bf8*)(h1b + (size_t)src0 * NH1 + kg * 8);
            bf8 ab1 = *(const bf8*)(h1b + (size_t)src1 * NH1 + kg * 8);
#pragma unroll
            for (int s = 0; s < 2; s++) {
                int my_et = s ? et1v : et0v;
                int my_dst = s ? dst1 : dst0;
                bf8 a = s ? ab1 : ab0;
                f4 c = (f4)0.0f;
                int pos = 0;
                while (pos < 16) {
                    int r = __shfl(my_et, pos);
                    unsigned long long bl = __ballot(my_et == r);
                    unsigned m16 = (unsigned)(bl & 0xFFFFull);
                    int run = __builtin_ctz(~(m16 >> pos));
                    int end = pos + run;
                    bf8 bb = *(const bf8*)(W2T + (size_t)r * (NH2 * NH1) + (size_t)l15 * NH1 + kg * 8);
                    bool use = (l15 >= pos) && (l15 < end);
                    c = __builtin_amdgcn_mfma_f32_16x16x32_bf16(use ? a : zero, bb, c, 0, 0, 0);
                    pos = end;
                }
#pragma unroll
                for (int j = 0; j < 4; j++) {
                    int eidx = kg * 4 + j;
                    int dst = __shfl(my_dst, eidx);
                    atomicAdd(out + (size_t)dst * NH2 + l15, c[j]);
                }
            }
        }
    }
    gridbar(bar, 5);

    // ================= P6: relu2 in place on out =================
    {
        int i = b * THR + t;                           // 262144 threads > 120000 elems
        if (i < NN * NH2 / 4) {
            float4 v = ((float4*)out)[i];
            v.x = fmaxf(v.x, 0.f); v.y = fmaxf(v.y, 0.f);
            v.z = fmaxf(v.z, 0.f); v.w = fmaxf(v.w, 0.f);
            ((float4*)out)[i] = v;
        }
    }
}

// ---------------- launch ----------------
extern "C" void kernel_launch(void* const* d_in, const int* in_sizes, int n_in,
                              void* d_out, int out_size, void* d_ws, size_t ws_size,
                              hipStream_t stream) {
    const float* x      = (const float*)d_in[0];
    const int*   ei     = (const int*)d_in[1];
    const int*   et     = (const int*)d_in[2];
    const float* xnorm  = (const float*)d_in[4];
    const float* embed  = (const float*)d_in[5];
    const float* basis1 = (const float*)d_in[6];
    const float* att1   = (const float*)d_in[7];
    const float* root1  = (const float*)d_in[8];
    const float* bias1  = (const float*)d_in[9];
    const float* basis2 = (const float*)d_in[10];
    const float* att2   = (const float*)d_in[11];
    const float* root2  = (const float*)d_in[12];
    const float* bias2  = (const float*)d_in[13];
    float* out = (float*)d_out;

    char* ws = (char*)d_ws;
    __bf16* embT = (__bf16*)(ws + 0);              //   262,144
    __bf16* W1T  = (__bf16*)(ws + 262144);         //   262,144
    __bf16* W2T  = (__bf16*)(ws + 524288);         //    65,536
    __bf16* h0b  = (__bf16*)(ws + 589824);         // 3,840,000
    float*  out1 = (float*) (ws + 4429824);        // 3,840,000
    __bf16* h1b  = (__bf16*)(ws + 8269824);        // 1,920,000
    int*    bar  = (int*)   (ws + 10189824);       //        64  (end ~10.2 MB)

    hipMemsetAsync(bar, 0, 64, stream);
    k_mega<<<NBLK, THR, 0, stream>>>(x, ei, et, xnorm, embed, basis1, att1, root1, bias1,
                                     basis2, att2, root2, bias2,
                                     embT, W1T, W2T, h0b, out1, h1b, out, bar);
}